// Round 3
// baseline (295.927 us; speedup 1.0000x reference)
//
#include <hip/hip_runtime.h>
#include <hip/hip_bf16.h>

#define BB 8
#define NN 4096
#define FF 64
#define HH 128
#define KNN 16

typedef __attribute__((ext_vector_type(8))) short bf16x8;
typedef __attribute__((ext_vector_type(4))) short bf16x4;
typedef __attribute__((ext_vector_type(4))) float f32x4;

// Fragment-ordered bf16 weight workspace offsets (in shorts)
#define OFF_iW2 0
#define OFF_fW1 16384
#define OFF_fW2 24576
#define OFF_sW1 40960
#define OFF_sW2 73728
#define HI_SZ   90112

// ---- reference-matching arithmetic (XLA-CPU style: FMA-contracted dot/sq) ----
__device__ __forceinline__ float sq3(float x, float y, float z) {
    return fmaf(z, z, fmaf(y, y, __fmul_rn(x, x)));
}
__device__ __forceinline__ float dist2f(float px, float py, float pz, float psq, float4 cc) {
    float t = fmaf(pz, cc.z, fmaf(py, cc.y, __fmul_rn(px, cc.x)));
    return __fsub_rn(__fadd_rn(psq, cc.w), __fmul_rn(2.0f, t));
}

// round-to-nearest-even f32 -> bf16 bits (finite inputs)
__device__ __forceinline__ short f2bf(float x) {
    unsigned u = __float_as_uint(x);
    u += 0x7fffu + ((u >> 16) & 1u);
    return (short)(u >> 16);
}
__device__ __forceinline__ float bf2f(short s) {
    return __uint_as_float(((unsigned)(unsigned short)s) << 16);
}

// ---------------- Kernel 1 (merged): coords pack + center, and weight hi/lo split ----------------
extern "C" __global__ __launch_bounds__(256)
void k_prep(const float* __restrict__ coords, float4* __restrict__ coords4, float* __restrict__ center,
            const float* __restrict__ iW2, const float* __restrict__ fW1,
            const float* __restrict__ fW2, const float* __restrict__ sW1,
            const float* __restrict__ sW2, short* __restrict__ wbf) {
    const int bx = blockIdx.x, tid = threadIdx.x;
    __shared__ float rx[256], ry[256], rz[256];
    if (bx < 8) {
        const int b = bx;
        float sx = 0.f, sy = 0.f, sz = 0.f;
        for (int n = tid; n < NN; n += 256) {
            const float* c = coords + (size_t)(b * NN + n) * 3;
            float x = c[0], y = c[1], z = c[2];
            coords4[b * NN + n] = make_float4(x, y, z, sq3(x, y, z));
            sx += x; sy += y; sz += z;
        }
        rx[tid] = sx; ry[tid] = sy; rz[tid] = sz;
        __syncthreads();
        for (int s = 128; s > 0; s >>= 1) {
            if (tid < s) { rx[tid] += rx[tid + s]; ry[tid] += ry[tid + s]; rz[tid] += rz[tid + s]; }
            __syncthreads();
        }
        if (tid == 0) {
            center[b * 4 + 0] = rx[0] * (1.0f / NN);
            center[b * 4 + 1] = ry[0] * (1.0f / NN);
            center[b * 4 + 2] = rz[0] * (1.0f / NN);
        }
    } else {
        // weight split: B-fragment layout for mfma_f32_16x16x32_bf16.
        // elem e -> j=e&7, lane=(e>>3)&63, ct=(e>>9)&7, kb=e>>12;
        // k = kb*32+(lane>>4)*8+j, n = ct*16+(lane&15).
        const int wb = bx - 8;        // 0..79
        const int w = wb >> 4;        // 0..4
        const int xb = wb & 15;       // 0..15
        const float* W; int K; int off;
        if (w == 0)      { W = iW2; K = 128; off = OFF_iW2; }
        else if (w == 1) { W = fW1; K = 64;  off = OFF_fW1; }
        else if (w == 2) { W = fW2; K = 128; off = OFF_fW2; }
        else if (w == 3) { W = sW1; K = 256; off = OFF_sW1; }
        else             { W = sW2; K = 128; off = OFF_sW2; }
        short* hi = wbf + off;
        short* lo = wbf + HI_SZ + off;
        const int total = K * 128;
        for (int e = xb * 256 + tid; e < total; e += 4096) {
            int j = e & 7, lane = (e >> 3) & 63, ct = (e >> 9) & 7, kb = e >> 12;
            int k = kb * 32 + (lane >> 4) * 8 + j;
            int n = ct * 16 + (lane & 15);
            float v = W[k * 128 + n];
            short h = f2bf(v);
            float r = v - bf2f(h);
            hi[e] = h; lo[e] = f2bf(r);
        }
    }
}

// Jacobi rotation on symmetric 3x3 (exact rotations, division-safe).
#define JROT(app, aqq, apq, arp, arq, vp0, vp1, vp2, vq0, vq1, vq2) { \
    float tau_ = (aqq - app) / (2.0f * apq); \
    float tt_ = copysignf(1.0f, tau_) / (fabsf(tau_) + sqrtf(1.0f + tau_ * tau_)); \
    if (apq == 0.0f) tt_ = 0.0f; \
    float cc_ = 1.0f / sqrtf(1.0f + tt_ * tt_); \
    float ss_ = tt_ * cc_; \
    float app_n = cc_*cc_*app - 2.0f*cc_*ss_*apq + ss_*ss_*aqq; \
    float aqq_n = ss_*ss_*app + 2.0f*cc_*ss_*apq + cc_*cc_*aqq; \
    float apq_n = cc_*ss_*(app - aqq) + (cc_*cc_ - ss_*ss_)*apq; \
    float arp_n = cc_*arp - ss_*arq; \
    float arq_n = ss_*arp + cc_*arq; \
    app = app_n; aqq = aqq_n; apq = apq_n; arp = arp_n; arq = arq_n; \
    float t0_ = cc_*vp0 - ss_*vq0, t1_ = cc_*vp1 - ss_*vq1, t2_ = cc_*vp2 - ss_*vq2; \
    vq0 = ss_*vp0 + cc_*vq0; vq1 = ss_*vp1 + cc_*vq1; vq2 = ss_*vp2 + cc_*vq2; \
    vp0 = t0_; vp1 = t1_; vp2 = t2_; }

#define SWAPF(a, b) { float sw_ = a; a = b; b = sw_; }

// compare-exchange: min -> a, max -> b (exact multiset op)
__device__ __forceinline__ void ce(float& a, float& b) {
    float mn = fminf(a, b);
    b = fmaxf(a, b);
    a = mn;
}

// Batcher odd-even mergesort, 16 floats ascending (63 CE vs bitonic's 80).
__device__ __forceinline__ void sort16(float (&d)[16]) {
    // OEMS(8) on [0..7]
    ce(d[0],d[1]); ce(d[2],d[3]); ce(d[0],d[2]); ce(d[1],d[3]); ce(d[1],d[2]);
    ce(d[4],d[5]); ce(d[6],d[7]); ce(d[4],d[6]); ce(d[5],d[7]); ce(d[5],d[6]);
    ce(d[0],d[4]); ce(d[2],d[6]); ce(d[2],d[4]);
    ce(d[1],d[5]); ce(d[3],d[7]); ce(d[3],d[5]);
    ce(d[1],d[2]); ce(d[3],d[4]); ce(d[5],d[6]);
    // OEMS(8) on [8..15]
    ce(d[8],d[9]); ce(d[10],d[11]); ce(d[8],d[10]); ce(d[9],d[11]); ce(d[9],d[10]);
    ce(d[12],d[13]); ce(d[14],d[15]); ce(d[12],d[14]); ce(d[13],d[15]); ce(d[13],d[14]);
    ce(d[8],d[12]); ce(d[10],d[14]); ce(d[10],d[12]);
    ce(d[9],d[13]); ce(d[11],d[15]); ce(d[11],d[13]);
    ce(d[9],d[10]); ce(d[11],d[12]); ce(d[13],d[14]);
    // OEM merge(8,8) on [0..15]
    ce(d[0],d[8]); ce(d[4],d[12]); ce(d[4],d[8]);
    ce(d[2],d[10]); ce(d[6],d[14]); ce(d[6],d[10]);
    ce(d[2],d[4]); ce(d[6],d[8]); ce(d[10],d[12]);
    ce(d[1],d[9]); ce(d[5],d[13]); ce(d[5],d[9]);
    ce(d[3],d[11]); ce(d[7],d[15]); ce(d[7],d[11]);
    ce(d[3],d[5]); ce(d[7],d[9]); ce(d[11],d[13]);
    ce(d[1],d[2]); ce(d[3],d[4]); ce(d[5],d[6]); ce(d[7],d[8]);
    ce(d[9],d[10]); ce(d[11],d[12]); ce(d[13],d[14]);
}

// dk (asc) + d (asc) -> dk = 16 smallest of the 32, ascending.
// In-place (mutates d, no t[16] temp): d_new[i] = min(dk[i], d_old[15-i]) for all i,
// then bitonic clean — identical values to the old t[]-based version.
__device__ __forceinline__ void merge16(float (&dk)[16], float (&d)[16]) {
#pragma unroll
    for (int i = 0; i < 8; i++) {
        float a  = fminf(dk[i], d[15 - i]);
        float b2 = fminf(dk[15 - i], d[i]);
        d[i] = a; d[15 - i] = b2;
    }
#pragma unroll
    for (int j = 8; j > 0; j >>= 1)
#pragma unroll
        for (int i = 0; i < 16; i++) {
            int l = i ^ j;
            if (l > i) ce(d[i], d[l]);
        }
#pragma unroll
    for (int i = 0; i < 16; i++) dk[i] = d[i];
}

// Bitonic sort 16 ints ascending (deterministic neighbor ordering).
__device__ __forceinline__ void sort16i(int (&d)[16]) {
#pragma unroll
    for (int k = 2; k <= 16; k <<= 1) {
#pragma unroll
        for (int j = k >> 1; j > 0; j >>= 1) {
#pragma unroll
            for (int i = 0; i < 16; i++) {
                int l = i ^ j;
                if (l > i) {
                    int a = d[i], bq = d[l];
                    int mn = a < bq ? a : bq;
                    int mx = a < bq ? bq : a;
                    if ((i & k) == 0) { d[i] = mn; d[l] = mx; }
                    else              { d[i] = mx; d[l] = mn; }
                }
            }
        }
    }
}

// ---------------- MLP helpers ----------------
__device__ __forceinline__ float gelu_exact(float x) {
    return 0.5f * x * (1.0f + erff(x * 0.70710678118654752440f));
}

// MFMA GEMM, 8-wave split: C[32][128] += A[32][K] @ W[K][128]; wave w owns
// col-tile w (cols w*16..w*16+15), both row-tiles. A bf16-hi in LDS [32][136],
// W exact via hi+lo bf16 fragment streams. A-layout: lane holds
// A[m=lane&15][k=quad*8+j]; C/D: col=lane&15, row=quad*4+reg (m89-verified).
template <int KB, bool INIT>
__device__ __forceinline__ void gemm_mfma(const short* Ab, const short* __restrict__ whi,
                                          const short* __restrict__ wlo,
                                          const float* __restrict__ bias,
                                          int wid, int lane, f32x4 acc[2]) {
    const int m16 = lane & 15, quad = lane >> 4;
    if (INIT) {
        float b0 = bias[wid * 16 + m16];
        acc[0] = (f32x4){b0, b0, b0, b0};
        acc[1] = acc[0];
    }
#pragma unroll 1
    for (int kb = 0; kb < KB; kb++) {
        bf16x8 a0 = *(const bf16x8*)(Ab + m16 * 136 + kb * 32 + quad * 8);
        bf16x8 a1 = *(const bf16x8*)(Ab + (m16 + 16) * 136 + kb * 32 + quad * 8);
        const int off = ((kb * 8 + wid) * 64 + lane) * 8;
        bf16x8 bh = *(const bf16x8*)(whi + off);
        bf16x8 bl = *(const bf16x8*)(wlo + off);
        acc[0] = __builtin_amdgcn_mfma_f32_16x16x32_bf16(a0, bh, acc[0], 0, 0, 0);
        acc[0] = __builtin_amdgcn_mfma_f32_16x16x32_bf16(a0, bl, acc[0], 0, 0, 0);
        acc[1] = __builtin_amdgcn_mfma_f32_16x16x32_bf16(a1, bh, acc[1], 0, 0, 0);
        acc[1] = __builtin_amdgcn_mfma_f32_16x16x32_bf16(a1, bl, acc[1], 0, 0, 0);
    }
}

// acc -> bf16 LDS [32][136] directly.
__device__ __forceinline__ void acc_to_bf(short* dst, f32x4 acc[2], int wid, int lane, bool dogelu) {
    const int m16 = lane & 15, quad = lane >> 4;
#pragma unroll
    for (int mt = 0; mt < 2; mt++)
#pragma unroll
        for (int i = 0; i < 4; i++) {
            float v = acc[mt][i];
            if (dogelu) v = gelu_exact(v);
            dst[(mt * 16 + quad * 4 + i) * 136 + wid * 16 + m16] = f2bf(v);
        }
}

// ---------------- Fused kernel: kNN + geometry + MFMA MLP per 32-point block ----------------
// 512 threads; thread = (pid = tid>>4, h = tid&15); candidate stripe g = j*16+h.
// Phase 1 is barrier-free: direct (L1/L2-resident) global candidate loads,
// butterfly merge entirely via intra-wave __shfl_xor (h = lane bits 0..3).
// __launch_bounds__(512, 8): forces the <=64-total-reg bucket -> 8 waves/EU
// (R1/R2 showed: 64-reg/8-wave beats 80-reg/4-wave even with spill).
// LDS 20352 B (no aliasing):
//   [0, 1024)       slist: 32 x 16 ushort strict-neighbor ids
//   [1024, 1536)    tlist: 32 x 8 ushort tie ids
//   [1536, 1792)    cnt_s/cnt_t: 32+32 int
//   [1792, 2816)    inv8: 32 x 8 f32 invariants (epilogue -> s6)
//   [2816, 2944)    sc: 32 f32 scalar accum
//   [2944, 11648)   Abf: [32][136] bf16 activations (phase 2)
//   [11648, 20352)  FHbf: [32][136] bf16
extern "C" __global__ __launch_bounds__(512, 8)
void k_fused(const float4* __restrict__ coords4, const float* __restrict__ center,
             const float* __restrict__ features, const short* __restrict__ wbf,
             const float* __restrict__ iW1, const float* __restrict__ ib1,
             const float* __restrict__ ib2,
             const float* __restrict__ fb1, const float* __restrict__ fb2,
             const float* __restrict__ sb1, const float* __restrict__ sb2,
             const float* __restrict__ gW, const float* __restrict__ gb,
             float* __restrict__ out) {
    const int blk = blockIdx.x;
    const int b = blk >> 7;
    const int chunk = blk & 127;
    const int tid = threadIdx.x;
    const int h = tid & 15;                      // stripe 0..15
    const int pid = tid >> 4;                    // point 0..31
    const int n = chunk * 32 + pid;
    const float4* __restrict__ C = coords4 + b * NN;

    __shared__ __align__(16) char smem[20352];
    unsigned short* slist = (unsigned short*)(smem);
    unsigned short* tlist = (unsigned short*)(smem + 1024);
    int* cnt_s = (int*)(smem + 1536);
    int* cnt_t = (int*)(smem + 1664);
    float* inv8 = (float*)(smem + 1792);
    float* sc   = (float*)(smem + 2816);
    short* Abf  = (short*)(smem + 2944);
    short* FHbf = (short*)(smem + 11648);

    if (tid < 32) { cnt_s[tid] = 0; cnt_t[tid] = 0; }

    float4 me = C[n];
    const float px = me.x, py = me.y, pz = me.z, psq = me.w;
    const float INF = __builtin_inff();
    // this thread's candidates: global index g = j*16 + h, j = 0..255.
    // self appears iff (n & 15) == h, at j = n >> 4.
    const int self_j = ((n & 15) == h) ? (n >> 4) : 256;

    // ======== PHASE 1 pass 1: per-thread exact top-16 of its 256 candidates ========
    float dk[KNN];
#pragma unroll
    for (int i = 0; i < KNN; i++) dk[i] = INF;

    for (int bt = 0; bt < 16; bt++) {
        float d[16];
#pragma unroll
        for (int i = 0; i < 16; i++) {
            float4 cc = C[(bt * 16 + i) * 16 + h];
            float dd = dist2f(px, py, pz, psq, cc);
            d[i] = (bt * 16 + i) == self_j ? INF : dd;
        }
        sort16(d);
        merge16(dk, d);
    }

    // ======== butterfly merge across the 16 stripe-threads (all intra-wave) ========
#pragma unroll
    for (int m = 1; m <= 8; m <<= 1) {
        float o[16];
#pragma unroll
        for (int i = 0; i < KNN; i++) o[i] = __shfl_xor(dk[i], m);
        merge16(dk, o);
    }
    const float d15 = dk[15];   // exact 16th-smallest (identical multiset => identical value)

    __syncthreads();            // cnt_s/cnt_t init visible to all

    // ======== pass 2: recover neighbor ids by threshold scan (atomic append) ========
    // <=15 strict (d15 is the 16th order statistic); ties appended racily but
    // the selected 16 are sorted deterministically in the epilogue.
#pragma unroll 4
    for (int j = 0; j < 256; j++) {
        float4 cc = C[j * 16 + h];
        float d = dist2f(px, py, pz, psq, cc);
        if (j != self_j && d <= d15) {
            if (d < d15) {
                int pos = atomicAdd(&cnt_s[pid], 1);
                if (pos < 16) slist[pid * 16 + pos] = (unsigned short)(j * 16 + h);
            } else {
                int pos = atomicAdd(&cnt_t[pid], 1);
                if (pos < 8) tlist[pid * 8 + pos] = (unsigned short)(j * 16 + h);
            }
        }
    }
    __syncthreads();

    // ======== epilogue: geometry (threads 0..31, one point each) ========
    if (tid < 32) {
        const int np = chunk * 32 + tid;
        float4 pme = C[np];
        int ns = cnt_s[tid]; ns = ns > 15 ? 15 : ns;
        int ids[16];
#pragma unroll
        for (int j = 0; j < 16; j++) {
            int tj = j - ns; tj = tj < 0 ? 0 : (tj > 7 ? 7 : tj);
            int sid = (int)slist[tid * 16 + j];
            int tie = (int)tlist[tid * 8 + tj];
            ids[j] = (j < ns) ? sid : tie;
        }
        sort16i(ids);           // deterministic (ascending global index) order

        float cxx = 0.f, cxy = 0.f, cxz = 0.f, cyy = 0.f, cyz = 0.f, czz = 0.f, radsum = 0.f;
#pragma unroll
        for (int j = 0; j < KNN; j++) {
            float4 cc = C[ids[j]];
            float rx = __fsub_rn(cc.x, pme.x), ry = __fsub_rn(cc.y, pme.y), rz = __fsub_rn(cc.z, pme.z);
            cxx = __fadd_rn(cxx, __fmul_rn(rx, rx));
            cxy = __fadd_rn(cxy, __fmul_rn(rx, ry));
            cxz = __fadd_rn(cxz, __fmul_rn(rx, rz));
            cyy = __fadd_rn(cyy, __fmul_rn(ry, ry));
            cyz = __fadd_rn(cyz, __fmul_rn(ry, rz));
            czz = __fadd_rn(czz, __fmul_rn(rz, rz));
            float rr = __fadd_rn(__fadd_rn(__fmul_rn(rx, rx), __fmul_rn(ry, ry)), __fmul_rn(rz, rz));
            radsum = __fadd_rn(radsum, sqrtf(rr));
        }
        const float inv_k = 1.0f / KNN;
        float a00 = cxx * inv_k, a01 = cxy * inv_k, a02 = cxz * inv_k;
        float a11 = cyy * inv_k, a12 = cyz * inv_k, a22 = czz * inv_k;

        float V00 = 1.f, V01 = 0.f, V02 = 0.f;
        float V10 = 0.f, V11 = 1.f, V12 = 0.f;
        float V20 = 0.f, V21 = 0.f, V22 = 1.f;
        for (int sweep = 0; sweep < 6; sweep++) {
            JROT(a00, a11, a01, a02, a12, V00, V10, V20, V01, V11, V21);
            JROT(a00, a22, a02, a01, a12, V00, V10, V20, V02, V12, V22);
            JROT(a11, a22, a12, a01, a02, V01, V11, V21, V02, V12, V22);
        }
        float e0 = a00, e1 = a11, e2 = a22;
        float x0 = V00, y0 = V10, z0 = V20;
        float x1 = V01, y1 = V11, z1 = V21;
        float x2 = V02, y2 = V12, z2 = V22;
        if (e0 > e1) { SWAPF(e0, e1); SWAPF(x0, x1); SWAPF(y0, y1); SWAPF(z0, z1); }
        if (e1 > e2) { SWAPF(e1, e2); SWAPF(x1, x2); SWAPF(y1, y2); SWAPF(z1, z2); }
        if (e0 > e1) { SWAPF(e0, e1); SWAPF(x0, x1); SWAPF(y0, y1); SWAPF(z0, z1); }

        float cx = center[b * 4 + 0], cy = center[b * 4 + 1], cz = center[b * 4 + 2];
        float ox = __fsub_rn(pme.x, cx), oy = __fsub_rn(pme.y, cy), oz = __fsub_rn(pme.z, cz);
        float dt = __fadd_rn(__fadd_rn(__fmul_rn(x0, ox), __fmul_rn(y0, oy)), __fmul_rn(z0, oz));
        float sgn = (dt >= 0.0f) ? 1.0f : -1.0f;
        x0 *= sgn; y0 *= sgn; z0 *= sgn;
        float nrm = sqrtf(__fadd_rn(__fadd_rn(__fmul_rn(x0, x0), __fmul_rn(y0, y0)), __fmul_rn(z0, z0)));
        float den = fmaxf(nrm, 1e-6f);
        x0 = x0 / den; y0 = y0 / den; z0 = z0 / den;

        float radius = radsum * inv_k;
        float crad = sqrtf(__fadd_rn(__fadd_rn(__fmul_rn(ox, ox), __fmul_rn(oy, oy)), __fmul_rn(oz, oz)));
        float esum = fmaxf(__fadd_rn(__fadd_rn(e0, e1), e2), 1e-6f);
        float dom = e2 / esum;

        float* ip = inv8 + tid * 8;
        ip[0] = e0; ip[1] = e1; ip[2] = e2; ip[3] = radius; ip[4] = crad; ip[5] = dom;
        ip[6] = 0.f; ip[7] = 0.f;

        float pd = __fadd_rn(__fadd_rn(__fmul_rn(pme.x, x0), __fmul_rn(pme.y, y0)), __fmul_rn(pme.z, z0));
        float4* o = (float4*)(out + (size_t)(b * NN + np) * 16);
        o[0] = make_float4(0.0f, x0, y0, -z0);
        o[1] = make_float4(-pd, x0, y0, z0);
        o[2] = make_float4(0.0f, 0.0f, 0.0f, pme.x);
        o[3] = make_float4(pme.y, pme.z, 1.0f, 0.0f);
        sc[tid] = gb[0];
    }
    __syncthreads();   // phase boundary: inv8/sc live

    // ======== PHASE 2: MFMA MLP (8 waves, wave w owns col-tile w) ========
    const int wid = tid >> 6, lane = tid & 63;
    const short* w_iW2h = wbf + OFF_iW2; const short* w_iW2l = wbf + HI_SZ + OFF_iW2;
    const short* w_fW1h = wbf + OFF_fW1; const short* w_fW1l = wbf + HI_SZ + OFF_fW1;
    const short* w_fW2h = wbf + OFF_fW2; const short* w_fW2l = wbf + HI_SZ + OFF_fW2;
    const short* w_sW1h = wbf + OFF_sW1; const short* w_sW1l = wbf + HI_SZ + OFF_sW1;
    const short* w_sW2h = wbf + OFF_sW2; const short* w_sW2l = wbf + HI_SZ + OFF_sW2;
    f32x4 acc[2];

    // s1: features (32 x 64) -> Abf bf16 (4 cols/thread)
    {
        int row = tid >> 4, c4 = (tid & 15) * 4;
        const float* s = features + (size_t)(b * NN + chunk * 32 + row) * FF + c4;
        float4 v = *(const float4*)s;
        bf16x4 pk;
        pk[0] = f2bf(v.x); pk[1] = f2bf(v.y); pk[2] = f2bf(v.z); pk[3] = f2bf(v.w);
        *(bf16x4*)(Abf + row * 136 + c4) = pk;
    }
    __syncthreads();

    // s2: L1b = gelu(feat @ fW1 + fb1)
    gemm_mfma<2, true>(Abf, w_fW1h, w_fW1l, fb1, wid, lane, acc);
    __syncthreads();
    acc_to_bf(Abf, acc, wid, lane, true);
    __syncthreads();

    // s4: feat_h = h @ fW2 + fb2 -> FHbf
    gemm_mfma<4, true>(Abf, w_fW2h, w_fW2l, fb2, wid, lane, acc);
    __syncthreads();
    acc_to_bf(FHbf, acc, wid, lane, false);

    // s6: L1a = gelu(inv @ iW1 + ib1)  (K=6, VALU; 2 rows x 4 cols/thread) -> Abf
    {
        const int cg = tid & 31, pg = tid >> 5;
        const int c0 = cg * 4, p0 = pg * 2;
        float4 bb = *(const float4*)(ib1 + c0);
        float a2[2][4];
#pragma unroll
        for (int i = 0; i < 2; i++) { a2[i][0] = bb.x; a2[i][1] = bb.y; a2[i][2] = bb.z; a2[i][3] = bb.w; }
#pragma unroll
        for (int k = 0; k < 6; k++) {
            float4 w = *(const float4*)(iW1 + k * HH + c0);
#pragma unroll
            for (int i = 0; i < 2; i++) {
                float a = inv8[(p0 + i) * 8 + k];
                a2[i][0] = fmaf(a, w.x, a2[i][0]);
                a2[i][1] = fmaf(a, w.y, a2[i][1]);
                a2[i][2] = fmaf(a, w.z, a2[i][2]);
                a2[i][3] = fmaf(a, w.w, a2[i][3]);
            }
        }
#pragma unroll
        for (int i = 0; i < 2; i++) {
            bf16x4 pk;
            pk[0] = f2bf(gelu_exact(a2[i][0])); pk[1] = f2bf(gelu_exact(a2[i][1]));
            pk[2] = f2bf(gelu_exact(a2[i][2])); pk[3] = f2bf(gelu_exact(a2[i][3]));
            *(bf16x4*)(Abf + (p0 + i) * 136 + c0) = pk;
        }
    }
    __syncthreads();

    // s8: inv_h = h @ iW2 + ib2 -> Abf
    gemm_mfma<4, true>(Abf, w_iW2h, w_iW2l, ib2, wid, lane, acc);
    __syncthreads();
    acc_to_bf(Abf, acc, wid, lane, false);
    __syncthreads();

    // s10: hidden-in = gelu(concat(inv_h, feat_h) @ sW1 + sb1)
    gemm_mfma<4, true>(Abf, w_sW1h, w_sW1l, sb1, wid, lane, acc);
    gemm_mfma<4, false>(FHbf, w_sW1h + 16384, w_sW1l + 16384, nullptr, wid, lane, acc);
    __syncthreads();
    acc_to_bf(Abf, acc, wid, lane, true);
    __syncthreads();

    // s12: hidden = h @ sW2 + sb2; scalar = hidden @ gW + gb
    gemm_mfma<4, true>(Abf, w_sW2h, w_sW2l, sb2, wid, lane, acc);
    {
        const int m16 = lane & 15, quad = lane >> 4;
        float g = gW[wid * 16 + m16];
#pragma unroll
        for (int mt = 0; mt < 2; mt++)
#pragma unroll
            for (int i = 0; i < 4; i++)
                atomicAdd(&sc[mt * 16 + quad * 4 + i], acc[mt][i] * g);
    }
    __syncthreads();
    if (tid < 32) out[(size_t)(b * NN + chunk * 32 + tid) * 16] = sc[tid];
}

// ---------------- launcher ----------------
extern "C" void kernel_launch(void* const* d_in, const int* in_sizes, int n_in,
                              void* d_out, int out_size, void* d_ws, size_t ws_size,
                              hipStream_t stream) {
    const float* coords   = (const float*)d_in[0];
    const float* features = (const float*)d_in[1];
    const float* iW1 = (const float*)d_in[2],  * ib1 = (const float*)d_in[3];
    const float* iW2 = (const float*)d_in[4],  * ib2 = (const float*)d_in[5];
    const float* fW1 = (const float*)d_in[6],  * fb1 = (const float*)d_in[7];
    const float* fW2 = (const float*)d_in[8],  * fb2 = (const float*)d_in[9];
    const float* sW1 = (const float*)d_in[10], * sb1 = (const float*)d_in[11];
    const float* sW2 = (const float*)d_in[12], * sb2 = (const float*)d_in[13];
    const float* gW  = (const float*)d_in[14], * gb  = (const float*)d_in[15];
    float* out = (float*)d_out;

    float* ws = (float*)d_ws;
    float4* coords4 = (float4*)ws;                        // 8*4096 float4 = 512 KB
    float* center = ws + BB * NN * 4;                     // 32 floats
    short* wbf = (short*)((char*)d_ws + 524416);          // 2*90112 shorts = 352 KB

    hipLaunchKernelGGL(k_prep, dim3(88), dim3(256), 0, stream,
                       coords, coords4, center, iW2, fW1, fW2, sW1, sW2, wbf);
    hipLaunchKernelGGL(k_fused, dim3(1024), dim3(512), 0, stream, coords4, center, features, wbf,
                       iW1, ib1, ib2, fb1, fb2, sb1, sb2, gW, gb, out);
}

// Round 4
// 263.760 us; speedup vs baseline: 1.1220x; 1.1220x over previous
//
#include <hip/hip_runtime.h>
#include <hip/hip_bf16.h>

#define BB 8
#define NN 4096
#define FF 64
#define HH 128
#define KNN 16

typedef __attribute__((ext_vector_type(8))) short bf16x8;
typedef __attribute__((ext_vector_type(4))) short bf16x4;
typedef __attribute__((ext_vector_type(4))) float f32x4;

// Fragment-ordered bf16 weight workspace offsets (in shorts)
#define OFF_iW2 0
#define OFF_fW1 16384
#define OFF_fW2 24576
#define OFF_sW1 40960
#define OFF_sW2 73728
#define HI_SZ   90112

// ---- reference-matching arithmetic (XLA-CPU style: FMA-contracted dot/sq) ----
__device__ __forceinline__ float sq3(float x, float y, float z) {
    return fmaf(z, z, fmaf(y, y, __fmul_rn(x, x)));
}
__device__ __forceinline__ float dist2f(float px, float py, float pz, float psq, float4 cc) {
    float t = fmaf(pz, cc.z, fmaf(py, cc.y, __fmul_rn(px, cc.x)));
    return __fsub_rn(__fadd_rn(psq, cc.w), __fmul_rn(2.0f, t));
}

// round-to-nearest-even f32 -> bf16 bits (finite inputs)
__device__ __forceinline__ short f2bf(float x) {
    unsigned u = __float_as_uint(x);
    u += 0x7fffu + ((u >> 16) & 1u);
    return (short)(u >> 16);
}
__device__ __forceinline__ float bf2f(short s) {
    return __uint_as_float(((unsigned)(unsigned short)s) << 16);
}

// ---------------- Kernel 1 (merged): coords pack + center, and weight hi/lo split ----------------
extern "C" __global__ __launch_bounds__(256)
void k_prep(const float* __restrict__ coords, float4* __restrict__ coords4, float* __restrict__ center,
            const float* __restrict__ iW2, const float* __restrict__ fW1,
            const float* __restrict__ fW2, const float* __restrict__ sW1,
            const float* __restrict__ sW2, short* __restrict__ wbf) {
    const int bx = blockIdx.x, tid = threadIdx.x;
    __shared__ float rx[256], ry[256], rz[256];
    if (bx < 8) {
        const int b = bx;
        float sx = 0.f, sy = 0.f, sz = 0.f;
        for (int n = tid; n < NN; n += 256) {
            const float* c = coords + (size_t)(b * NN + n) * 3;
            float x = c[0], y = c[1], z = c[2];
            coords4[b * NN + n] = make_float4(x, y, z, sq3(x, y, z));
            sx += x; sy += y; sz += z;
        }
        rx[tid] = sx; ry[tid] = sy; rz[tid] = sz;
        __syncthreads();
        for (int s = 128; s > 0; s >>= 1) {
            if (tid < s) { rx[tid] += rx[tid + s]; ry[tid] += ry[tid + s]; rz[tid] += rz[tid + s]; }
            __syncthreads();
        }
        if (tid == 0) {
            center[b * 4 + 0] = rx[0] * (1.0f / NN);
            center[b * 4 + 1] = ry[0] * (1.0f / NN);
            center[b * 4 + 2] = rz[0] * (1.0f / NN);
        }
    } else {
        // weight split: B-fragment layout for mfma_f32_16x16x32_bf16.
        const int wb = bx - 8;        // 0..79
        const int w = wb >> 4;        // 0..4
        const int xb = wb & 15;       // 0..15
        const float* W; int K; int off;
        if (w == 0)      { W = iW2; K = 128; off = OFF_iW2; }
        else if (w == 1) { W = fW1; K = 64;  off = OFF_fW1; }
        else if (w == 2) { W = fW2; K = 128; off = OFF_fW2; }
        else if (w == 3) { W = sW1; K = 256; off = OFF_sW1; }
        else             { W = sW2; K = 128; off = OFF_sW2; }
        short* hi = wbf + off;
        short* lo = wbf + HI_SZ + off;
        const int total = K * 128;
        for (int e = xb * 256 + tid; e < total; e += 4096) {
            int j = e & 7, lane = (e >> 3) & 63, ct = (e >> 9) & 7, kb = e >> 12;
            int k = kb * 32 + (lane >> 4) * 8 + j;
            int n = ct * 16 + (lane & 15);
            float v = W[k * 128 + n];
            short h = f2bf(v);
            float r = v - bf2f(h);
            hi[e] = h; lo[e] = f2bf(r);
        }
    }
}

// Jacobi rotation on symmetric 3x3 (exact rotations, division-safe).
#define JROT(app, aqq, apq, arp, arq, vp0, vp1, vp2, vq0, vq1, vq2) { \
    float tau_ = (aqq - app) / (2.0f * apq); \
    float tt_ = copysignf(1.0f, tau_) / (fabsf(tau_) + sqrtf(1.0f + tau_ * tau_)); \
    if (apq == 0.0f) tt_ = 0.0f; \
    float cc_ = 1.0f / sqrtf(1.0f + tt_ * tt_); \
    float ss_ = tt_ * cc_; \
    float app_n = cc_*cc_*app - 2.0f*cc_*ss_*apq + ss_*ss_*aqq; \
    float aqq_n = ss_*ss_*app + 2.0f*cc_*ss_*apq + cc_*cc_*aqq; \
    float apq_n = cc_*ss_*(app - aqq) + (cc_*cc_ - ss_*ss_)*apq; \
    float arp_n = cc_*arp - ss_*arq; \
    float arq_n = ss_*arp + cc_*arq; \
    app = app_n; aqq = aqq_n; apq = apq_n; arp = arp_n; arq = arq_n; \
    float t0_ = cc_*vp0 - ss_*vq0, t1_ = cc_*vp1 - ss_*vq1, t2_ = cc_*vp2 - ss_*vq2; \
    vq0 = ss_*vp0 + cc_*vq0; vq1 = ss_*vp1 + cc_*vq1; vq2 = ss_*vp2 + cc_*vq2; \
    vp0 = t0_; vp1 = t1_; vp2 = t2_; }

#define SWAPF(a, b) { float sw_ = a; a = b; b = sw_; }

// compare-exchange: min -> a, max -> b (exact multiset op)
__device__ __forceinline__ void ce(float& a, float& b) {
    float mn = fminf(a, b);
    b = fmaxf(a, b);
    a = mn;
}

// Batcher odd-even mergesort, 16 floats ascending (63 CE vs bitonic's 80).
__device__ __forceinline__ void sort16(float (&d)[16]) {
    ce(d[0],d[1]); ce(d[2],d[3]); ce(d[0],d[2]); ce(d[1],d[3]); ce(d[1],d[2]);
    ce(d[4],d[5]); ce(d[6],d[7]); ce(d[4],d[6]); ce(d[5],d[7]); ce(d[5],d[6]);
    ce(d[0],d[4]); ce(d[2],d[6]); ce(d[2],d[4]);
    ce(d[1],d[5]); ce(d[3],d[7]); ce(d[3],d[5]);
    ce(d[1],d[2]); ce(d[3],d[4]); ce(d[5],d[6]);
    ce(d[8],d[9]); ce(d[10],d[11]); ce(d[8],d[10]); ce(d[9],d[11]); ce(d[9],d[10]);
    ce(d[12],d[13]); ce(d[14],d[15]); ce(d[12],d[14]); ce(d[13],d[15]); ce(d[13],d[14]);
    ce(d[8],d[12]); ce(d[10],d[14]); ce(d[10],d[12]);
    ce(d[9],d[13]); ce(d[11],d[15]); ce(d[11],d[13]);
    ce(d[9],d[10]); ce(d[11],d[12]); ce(d[13],d[14]);
    ce(d[0],d[8]); ce(d[4],d[12]); ce(d[4],d[8]);
    ce(d[2],d[10]); ce(d[6],d[14]); ce(d[6],d[10]);
    ce(d[2],d[4]); ce(d[6],d[8]); ce(d[10],d[12]);
    ce(d[1],d[9]); ce(d[5],d[13]); ce(d[5],d[9]);
    ce(d[3],d[11]); ce(d[7],d[15]); ce(d[7],d[11]);
    ce(d[3],d[5]); ce(d[7],d[9]); ce(d[11],d[13]);
    ce(d[1],d[2]); ce(d[3],d[4]); ce(d[5],d[6]); ce(d[7],d[8]);
    ce(d[9],d[10]); ce(d[11],d[12]); ce(d[13],d[14]);
}

// dk (asc) + d (asc) -> dk = 16 smallest of the 32, ascending.
// In-place (mutates d): d_new[k] = min(dk[k], d_old[15-k]), then bitonic clean.
__device__ __forceinline__ void merge16(float (&dk)[16], float (&d)[16]) {
#pragma unroll
    for (int i = 0; i < 8; i++) {
        float a  = fminf(dk[i], d[15 - i]);
        float b2 = fminf(dk[15 - i], d[i]);
        d[i] = a; d[15 - i] = b2;
    }
#pragma unroll
    for (int j = 8; j > 0; j >>= 1)
#pragma unroll
        for (int i = 0; i < 16; i++) {
            int l = i ^ j;
            if (l > i) ce(d[i], d[l]);
        }
#pragma unroll
    for (int i = 0; i < 16; i++) dk[i] = d[i];
}

// Bitonic sort 16 ints ascending (deterministic neighbor ordering).
__device__ __forceinline__ void sort16i(int (&d)[16]) {
#pragma unroll
    for (int k = 2; k <= 16; k <<= 1) {
#pragma unroll
        for (int j = k >> 1; j > 0; j >>= 1) {
#pragma unroll
            for (int i = 0; i < 16; i++) {
                int l = i ^ j;
                if (l > i) {
                    int a = d[i], bq = d[l];
                    int mn = a < bq ? a : bq;
                    int mx = a < bq ? bq : a;
                    if ((i & k) == 0) { d[i] = mn; d[l] = mx; }
                    else              { d[i] = mx; d[l] = mn; }
                }
            }
        }
    }
}

// ---------------- k_knn: kNN + geometry, NO MFMA (full 64-reg bucket for selection) ----------------
// 512 threads; thread = (pid = tid>>4, h = tid&15); candidate stripe g-local = j16*16+h.
// LDS tile staging (coalesced) + all-shfl butterfly (h = lane bits 0..3).
// LDS ~18.2 KB; __launch_bounds__(512,8) -> 8 waves/EU, selection state (~48-56 regs)
// fits the 64-reg bucket because no AGPR/MFMA reservations exist in this kernel.
extern "C" __global__ __launch_bounds__(512, 8)
void k_knn(const float4* __restrict__ coords4, const float* __restrict__ center,
           float* __restrict__ inv8g, float* __restrict__ out) {
    const int blk = blockIdx.x;
    const int b = blk >> 7;
    const int chunk = blk & 127;
    const int tid = threadIdx.x;
    const int h = tid & 15;                      // stripe 0..15
    const int pid = tid >> 4;                    // point 0..31
    const int n = chunk * 32 + pid;
    const float4* __restrict__ C = coords4 + b * NN;

    __shared__ __align__(16) float4 tile[1024];          // 16 KB: one round of 1024 candidates
    __shared__ unsigned short slist[512];                // 32 x 16 strict ids
    __shared__ unsigned short tlist[256];                // 32 x 8 tie ids
    __shared__ int cnt_s[32];
    __shared__ int cnt_t[32];

    if (tid < 32) { cnt_s[tid] = 0; cnt_t[tid] = 0; }

    float4 me = C[n];
    const float px = me.x, py = me.y, pz = me.z, psq = me.w;
    const float INF = __builtin_inff();

    // ======== pass 1: per-thread exact top-16 of its 256 striped candidates ========
    float dk[KNN];
#pragma unroll
    for (int i = 0; i < KNN; i++) dk[i] = INF;

    for (int r = 0; r < 4; r++) {
        __syncthreads();
        tile[tid] = C[r * 1024 + tid];
        tile[tid + 512] = C[r * 1024 + tid + 512];
        __syncthreads();
#pragma unroll
        for (int bt = 0; bt < 4; bt++) {
            float d[16];
#pragma unroll
            for (int i = 0; i < 16; i++) {
                float4 cc = tile[bt * 256 + i * 16 + h];
                float dd = dist2f(px, py, pz, psq, cc);
                int g = r * 1024 + bt * 256 + i * 16 + h;
                d[i] = (g == n) ? INF : dd;
            }
            sort16(d);
            merge16(dk, d);
        }
    }

    // ======== butterfly merge across the 16 stripe-threads (all intra-wave) ========
#pragma unroll
    for (int m = 1; m <= 8; m <<= 1) {
        float o[16];
#pragma unroll
        for (int i = 0; i < KNN; i++) o[i] = __shfl_xor(dk[i], m);
        merge16(dk, o);
    }
    const float d15 = dk[15];   // exact 16th-smallest (identical multiset => identical value)

    // ======== pass 2: recover neighbor ids by threshold scan (atomic append) ========
    for (int r = 0; r < 4; r++) {
        __syncthreads();
        tile[tid] = C[r * 1024 + tid];
        tile[tid + 512] = C[r * 1024 + tid + 512];
        __syncthreads();
#pragma unroll 4
        for (int j16 = 0; j16 < 64; j16++) {
            float4 cc = tile[j16 * 16 + h];
            float d = dist2f(px, py, pz, psq, cc);
            int g = r * 1024 + j16 * 16 + h;
            if (g != n && d <= d15) {
                if (d < d15) {
                    int pos = atomicAdd(&cnt_s[pid], 1);
                    if (pos < 16) slist[pid * 16 + pos] = (unsigned short)g;
                } else {
                    int pos = atomicAdd(&cnt_t[pid], 1);
                    if (pos < 8) tlist[pid * 8 + pos] = (unsigned short)g;
                }
            }
        }
    }
    __syncthreads();

    // ======== geometry epilogue (threads 0..31, one point each) ========
    if (tid < 32) {
        const int np = chunk * 32 + tid;
        float4 pme = C[np];
        int ns = cnt_s[tid]; ns = ns > 15 ? 15 : ns;
        int ids[16];
#pragma unroll
        for (int j = 0; j < 16; j++) {
            int tj = j - ns; tj = tj < 0 ? 0 : (tj > 7 ? 7 : tj);
            int sid = (int)slist[tid * 16 + j];
            int tie = (int)tlist[tid * 8 + tj];
            ids[j] = (j < ns) ? sid : tie;
        }
        sort16i(ids);           // deterministic (ascending global index) order

        float cxx = 0.f, cxy = 0.f, cxz = 0.f, cyy = 0.f, cyz = 0.f, czz = 0.f, radsum = 0.f;
#pragma unroll
        for (int j = 0; j < KNN; j++) {
            float4 cc = C[ids[j]];
            float rx = __fsub_rn(cc.x, pme.x), ry = __fsub_rn(cc.y, pme.y), rz = __fsub_rn(cc.z, pme.z);
            cxx = __fadd_rn(cxx, __fmul_rn(rx, rx));
            cxy = __fadd_rn(cxy, __fmul_rn(rx, ry));
            cxz = __fadd_rn(cxz, __fmul_rn(rx, rz));
            cyy = __fadd_rn(cyy, __fmul_rn(ry, ry));
            cyz = __fadd_rn(cyz, __fmul_rn(ry, rz));
            czz = __fadd_rn(czz, __fmul_rn(rz, rz));
            float rr = __fadd_rn(__fadd_rn(__fmul_rn(rx, rx), __fmul_rn(ry, ry)), __fmul_rn(rz, rz));
            radsum = __fadd_rn(radsum, sqrtf(rr));
        }
        const float inv_k = 1.0f / KNN;
        float a00 = cxx * inv_k, a01 = cxy * inv_k, a02 = cxz * inv_k;
        float a11 = cyy * inv_k, a12 = cyz * inv_k, a22 = czz * inv_k;

        float V00 = 1.f, V01 = 0.f, V02 = 0.f;
        float V10 = 0.f, V11 = 1.f, V12 = 0.f;
        float V20 = 0.f, V21 = 0.f, V22 = 1.f;
        for (int sweep = 0; sweep < 6; sweep++) {
            JROT(a00, a11, a01, a02, a12, V00, V10, V20, V01, V11, V21);
            JROT(a00, a22, a02, a01, a12, V00, V10, V20, V02, V12, V22);
            JROT(a11, a22, a12, a01, a02, V01, V11, V21, V02, V12, V22);
        }
        float e0 = a00, e1 = a11, e2 = a22;
        float x0 = V00, y0 = V10, z0 = V20;
        float x1 = V01, y1 = V11, z1 = V21;
        float x2 = V02, y2 = V12, z2 = V22;
        if (e0 > e1) { SWAPF(e0, e1); SWAPF(x0, x1); SWAPF(y0, y1); SWAPF(z0, z1); }
        if (e1 > e2) { SWAPF(e1, e2); SWAPF(x1, x2); SWAPF(y1, y2); SWAPF(z1, z2); }
        if (e0 > e1) { SWAPF(e0, e1); SWAPF(x0, x1); SWAPF(y0, y1); SWAPF(z0, z1); }

        float cx = center[b * 4 + 0], cy = center[b * 4 + 1], cz = center[b * 4 + 2];
        float ox = __fsub_rn(pme.x, cx), oy = __fsub_rn(pme.y, cy), oz = __fsub_rn(pme.z, cz);
        float dt = __fadd_rn(__fadd_rn(__fmul_rn(x0, ox), __fmul_rn(y0, oy)), __fmul_rn(z0, oz));
        float sgn = (dt >= 0.0f) ? 1.0f : -1.0f;
        x0 *= sgn; y0 *= sgn; z0 *= sgn;
        float nrm = sqrtf(__fadd_rn(__fadd_rn(__fmul_rn(x0, x0), __fmul_rn(y0, y0)), __fmul_rn(z0, z0)));
        float den = fmaxf(nrm, 1e-6f);
        x0 = x0 / den; y0 = y0 / den; z0 = z0 / den;

        float radius = radsum * inv_k;
        float crad = sqrtf(__fadd_rn(__fadd_rn(__fmul_rn(ox, ox), __fmul_rn(oy, oy)), __fmul_rn(oz, oz)));
        float esum = fmaxf(__fadd_rn(__fadd_rn(e0, e1), e2), 1e-6f);
        float dom = e2 / esum;

        float* ip = inv8g + (size_t)(b * NN + np) * 8;
        ip[0] = e0; ip[1] = e1; ip[2] = e2; ip[3] = radius; ip[4] = crad; ip[5] = dom;
        ip[6] = 0.f; ip[7] = 0.f;

        float pd = __fadd_rn(__fadd_rn(__fmul_rn(pme.x, x0), __fmul_rn(pme.y, y0)), __fmul_rn(pme.z, z0));
        float4* o = (float4*)(out + (size_t)(b * NN + np) * 16);
        o[0] = make_float4(0.0f, x0, y0, -z0);
        o[1] = make_float4(-pd, x0, y0, z0);
        o[2] = make_float4(0.0f, 0.0f, 0.0f, pme.x);
        o[3] = make_float4(pme.y, pme.z, 1.0f, 0.0f);
    }
}

// ---------------- MLP helpers ----------------
__device__ __forceinline__ float gelu_exact(float x) {
    return 0.5f * x * (1.0f + erff(x * 0.70710678118654752440f));
}

// MFMA GEMM, 8-wave split: C[32][128] += A[32][K] @ W[K][128]; wave w owns
// col-tile w, both row-tiles. A bf16-hi in LDS [32][136]; W exact via hi+lo
// bf16 fragment streams. A: lane holds A[m=lane&15][k=quad*8+j];
// C/D: col=lane&15, row=quad*4+reg (m89-verified).
template <int KB, bool INIT>
__device__ __forceinline__ void gemm_mfma(const short* Ab, const short* __restrict__ whi,
                                          const short* __restrict__ wlo,
                                          const float* __restrict__ bias,
                                          int wid, int lane, f32x4 acc[2]) {
    const int m16 = lane & 15, quad = lane >> 4;
    if (INIT) {
        float b0 = bias[wid * 16 + m16];
        acc[0] = (f32x4){b0, b0, b0, b0};
        acc[1] = acc[0];
    }
#pragma unroll 1
    for (int kb = 0; kb < KB; kb++) {
        bf16x8 a0 = *(const bf16x8*)(Ab + m16 * 136 + kb * 32 + quad * 8);
        bf16x8 a1 = *(const bf16x8*)(Ab + (m16 + 16) * 136 + kb * 32 + quad * 8);
        const int off = ((kb * 8 + wid) * 64 + lane) * 8;
        bf16x8 bh = *(const bf16x8*)(whi + off);
        bf16x8 bl = *(const bf16x8*)(wlo + off);
        acc[0] = __builtin_amdgcn_mfma_f32_16x16x32_bf16(a0, bh, acc[0], 0, 0, 0);
        acc[0] = __builtin_amdgcn_mfma_f32_16x16x32_bf16(a0, bl, acc[0], 0, 0, 0);
        acc[1] = __builtin_amdgcn_mfma_f32_16x16x32_bf16(a1, bh, acc[1], 0, 0, 0);
        acc[1] = __builtin_amdgcn_mfma_f32_16x16x32_bf16(a1, bl, acc[1], 0, 0, 0);
    }
}

// acc -> bf16 LDS [32][136] directly.
__device__ __forceinline__ void acc_to_bf(short* dst, f32x4 acc[2], int wid, int lane, bool dogelu) {
    const int m16 = lane & 15, quad = lane >> 4;
#pragma unroll
    for (int mt = 0; mt < 2; mt++)
#pragma unroll
        for (int i = 0; i < 4; i++) {
            float v = acc[mt][i];
            if (dogelu) v = gelu_exact(v);
            dst[(mt * 16 + quad * 4 + i) * 136 + wid * 16 + m16] = f2bf(v);
        }
}

// ---------------- k_mlp: MFMA MLP per 32-point chunk (no kNN state) ----------------
// LDS 18.6 KB; ~48 regs incl AGPR -> clean 8 waves/EU, no spill.
extern "C" __global__ __launch_bounds__(512, 8)
void k_mlp(const float* __restrict__ features, const short* __restrict__ wbf,
           const float* __restrict__ iW1, const float* __restrict__ ib1,
           const float* __restrict__ ib2,
           const float* __restrict__ fb1, const float* __restrict__ fb2,
           const float* __restrict__ sb1, const float* __restrict__ sb2,
           const float* __restrict__ gW, const float* __restrict__ gb,
           const float* __restrict__ inv8g, float* __restrict__ out) {
    const int blk = blockIdx.x;
    const int b = blk >> 7;
    const int chunk = blk & 127;
    const int tid = threadIdx.x;

    __shared__ __align__(16) float inv8[256];    // 32 x 8 invariants
    __shared__ float sc[32];
    __shared__ __align__(16) short Abf[32 * 136];
    __shared__ __align__(16) short FHbf[32 * 136];

    const int wid = tid >> 6, lane = tid & 63;
    const short* w_iW2h = wbf + OFF_iW2; const short* w_iW2l = wbf + HI_SZ + OFF_iW2;
    const short* w_fW1h = wbf + OFF_fW1; const short* w_fW1l = wbf + HI_SZ + OFF_fW1;
    const short* w_fW2h = wbf + OFF_fW2; const short* w_fW2l = wbf + HI_SZ + OFF_fW2;
    const short* w_sW1h = wbf + OFF_sW1; const short* w_sW1l = wbf + HI_SZ + OFF_sW1;
    const short* w_sW2h = wbf + OFF_sW2; const short* w_sW2l = wbf + HI_SZ + OFF_sW2;
    f32x4 acc[2];

    // s0: stage invariants + sc init; s1: features (32 x 64) -> Abf bf16
    if (tid < 256) inv8[tid] = inv8g[(size_t)(b * NN + chunk * 32) * 8 + tid];
    if (tid < 32) sc[tid] = gb[0];
    {
        int row = tid >> 4, c4 = (tid & 15) * 4;
        const float* s = features + (size_t)(b * NN + chunk * 32 + row) * FF + c4;
        float4 v = *(const float4*)s;
        bf16x4 pk;
        pk[0] = f2bf(v.x); pk[1] = f2bf(v.y); pk[2] = f2bf(v.z); pk[3] = f2bf(v.w);
        *(bf16x4*)(Abf + row * 136 + c4) = pk;
    }
    __syncthreads();

    // s2: L1b = gelu(feat @ fW1 + fb1)
    gemm_mfma<2, true>(Abf, w_fW1h, w_fW1l, fb1, wid, lane, acc);
    __syncthreads();
    acc_to_bf(Abf, acc, wid, lane, true);
    __syncthreads();

    // s4: feat_h = h @ fW2 + fb2 -> FHbf
    gemm_mfma<4, true>(Abf, w_fW2h, w_fW2l, fb2, wid, lane, acc);
    __syncthreads();
    acc_to_bf(FHbf, acc, wid, lane, false);

    // s6: L1a = gelu(inv @ iW1 + ib1)  (K=6, VALU; 2 rows x 4 cols/thread) -> Abf
    {
        const int cg = tid & 31, pg = tid >> 5;
        const int c0 = cg * 4, p0 = pg * 2;
        float4 bb = *(const float4*)(ib1 + c0);
        float a2[2][4];
#pragma unroll
        for (int i = 0; i < 2; i++) { a2[i][0] = bb.x; a2[i][1] = bb.y; a2[i][2] = bb.z; a2[i][3] = bb.w; }
#pragma unroll
        for (int k = 0; k < 6; k++) {
            float4 w = *(const float4*)(iW1 + k * HH + c0);
#pragma unroll
            for (int i = 0; i < 2; i++) {
                float a = inv8[(p0 + i) * 8 + k];
                a2[i][0] = fmaf(a, w.x, a2[i][0]);
                a2[i][1] = fmaf(a, w.y, a2[i][1]);
                a2[i][2] = fmaf(a, w.z, a2[i][2]);
                a2[i][3] = fmaf(a, w.w, a2[i][3]);
            }
        }
#pragma unroll
        for (int i = 0; i < 2; i++) {
            bf16x4 pk;
            pk[0] = f2bf(gelu_exact(a2[i][0])); pk[1] = f2bf(gelu_exact(a2[i][1]));
            pk[2] = f2bf(gelu_exact(a2[i][2])); pk[3] = f2bf(gelu_exact(a2[i][3]));
            *(bf16x4*)(Abf + (p0 + i) * 136 + c0) = pk;
        }
    }
    __syncthreads();

    // s8: inv_h = h @ iW2 + ib2 -> Abf
    gemm_mfma<4, true>(Abf, w_iW2h, w_iW2l, ib2, wid, lane, acc);
    __syncthreads();
    acc_to_bf(Abf, acc, wid, lane, false);
    __syncthreads();

    // s10: hidden-in = gelu(concat(inv_h, feat_h) @ sW1 + sb1)
    gemm_mfma<4, true>(Abf, w_sW1h, w_sW1l, sb1, wid, lane, acc);
    gemm_mfma<4, false>(FHbf, w_sW1h + 16384, w_sW1l + 16384, nullptr, wid, lane, acc);
    __syncthreads();
    acc_to_bf(Abf, acc, wid, lane, true);
    __syncthreads();

    // s12: hidden = h @ sW2 + sb2; scalar = hidden @ gW + gb
    gemm_mfma<4, true>(Abf, w_sW2h, w_sW2l, sb2, wid, lane, acc);
    {
        const int m16 = lane & 15, quad = lane >> 4;
        float g = gW[wid * 16 + m16];
#pragma unroll
        for (int mt = 0; mt < 2; mt++)
#pragma unroll
            for (int i = 0; i < 4; i++)
                atomicAdd(&sc[mt * 16 + quad * 4 + i], acc[mt][i] * g);
    }
    __syncthreads();
    if (tid < 32) out[(size_t)(b * NN + chunk * 32 + tid) * 16] = sc[tid];
}

// ---------------- launcher ----------------
extern "C" void kernel_launch(void* const* d_in, const int* in_sizes, int n_in,
                              void* d_out, int out_size, void* d_ws, size_t ws_size,
                              hipStream_t stream) {
    const float* coords   = (const float*)d_in[0];
    const float* features = (const float*)d_in[1];
    const float* iW1 = (const float*)d_in[2],  * ib1 = (const float*)d_in[3];
    const float* iW2 = (const float*)d_in[4],  * ib2 = (const float*)d_in[5];
    const float* fW1 = (const float*)d_in[6],  * fb1 = (const float*)d_in[7];
    const float* fW2 = (const float*)d_in[8],  * fb2 = (const float*)d_in[9];
    const float* sW1 = (const float*)d_in[10], * sb1 = (const float*)d_in[11];
    const float* sW2 = (const float*)d_in[12], * sb2 = (const float*)d_in[13];
    const float* gW  = (const float*)d_in[14], * gb  = (const float*)d_in[15];
    float* out = (float*)d_out;

    char* ws = (char*)d_ws;
    float4* coords4 = (float4*)ws;                        // 512 KB            [0, 524288)
    float* center   = (float*)(ws + 524288);              // 128 B             [524288, 524416)
    short* wbf      = (short*)(ws + 524416);              // 352 KB            [524416, 884864)
    float* inv8g    = (float*)(ws + 884864);              // 1 MB              [884864, 1933440)

    hipLaunchKernelGGL(k_prep, dim3(88), dim3(256), 0, stream,
                       coords, coords4, center, iW2, fW1, fW2, sW1, sW2, wbf);
    hipLaunchKernelGGL(k_knn, dim3(1024), dim3(512), 0, stream, coords4, center, inv8g, out);
    hipLaunchKernelGGL(k_mlp, dim3(1024), dim3(512), 0, stream, features, wbf,
                       iW1, ib1, ib2, fb1, fb2, sb1, sb2, gW, gb, inv8g, out);
}